// Round 1
// baseline (140.143 us; speedup 1.0000x reference)
//
#include <hip/hip_runtime.h>
#include <math.h>

#define NUM_GRAPHS 512
#define D 128

__device__ inline int lower_bound_i(const int* __restrict__ b, int n, int v) {
    int lo = 0, hi = n;
    while (lo < hi) {
        int mid = (lo + hi) >> 1;
        if (b[mid] < v) lo = mid + 1; else hi = mid;
    }
    return lo;
}

__device__ inline float wave_sum(float v) {
#pragma unroll
    for (int off = 32; off > 0; off >>= 1) v += __shfl_xor(v, off, 64);
    return v;
}

// Pass 1: per-segment sums (batch sorted -> contiguous rows, no atomics).
// grid (NUM_GRAPHS, 2), block 256. Thread t: row-group r = t>>6, float2 col c = t&63.
__global__ void seg_sum_kernel(const float* __restrict__ z1,
                               const float* __restrict__ z2,
                               const int* __restrict__ b1,
                               const int* __restrict__ b2,
                               float* __restrict__ g1,
                               float* __restrict__ g2,
                               int N) {
    const int s = blockIdx.x;
    const int w = blockIdx.y;
    const float* z = w ? z2 : z1;
    const int*   b = w ? b2 : b1;
    float*       g = w ? g2 : g1;

    const int start = lower_bound_i(b, N, s);
    const int end   = lower_bound_i(b, N, s + 1);

    const int t = threadIdx.x;
    const int r = t >> 6;   // 0..3
    const int c = t & 63;   // float2 index within row
    const float2* Z2 = reinterpret_cast<const float2*>(z);

    float2 acc = make_float2(0.f, 0.f);
    int row = start + r;
    // unroll by 2 (rows row, row+4) for more loads in flight
    for (; row + 4 < end; row += 8) {
        float2 a = Z2[(size_t)row * 64 + c];
        float2 d = Z2[(size_t)(row + 4) * 64 + c];
        acc.x += a.x + d.x;
        acc.y += a.y + d.y;
    }
    for (; row < end; row += 4) {
        float2 a = Z2[(size_t)row * 64 + c];
        acc.x += a.x;
        acc.y += a.y;
    }

    __shared__ float2 lred[3][64];
    if (r > 0) lred[r - 1][c] = acc;
    __syncthreads();
    if (r == 0) {
        acc.x += lred[0][c].x + lred[1][c].x + lred[2][c].x;
        acc.y += lred[0][c].y + lred[1][c].y + lred[2][c].y;
        reinterpret_cast<float2*>(g)[(size_t)s * 64 + c] = acc;
    }
}

// Pass 2: per-row dots vs normalized g vectors + JSD diff, accumulate sum of d^2.
// grid (NUM_GRAPHS, 2), block 256 = 4 waves; one wave per row per iteration.
__global__ void dots_kernel(const float* __restrict__ z1,
                            const float* __restrict__ z2,
                            const int* __restrict__ b1,
                            const int* __restrict__ b2,
                            const float* __restrict__ g1,
                            const float* __restrict__ g2,
                            float* __restrict__ sums,
                            int N) {
    const int s = blockIdx.x;
    const int w = blockIdx.y;
    const float* z  = w ? z2 : z1;
    const int*   b  = w ? b2 : b1;
    const float* gp = w ? g2 : g1;   // positive: own modality's pooled vec
    const float* gc = w ? g1 : g2;   // cross: other modality's pooled vec

    const int start = lower_bound_i(b, N, s);
    const int end   = lower_bound_i(b, N, s + 1);

    const int t    = threadIdx.x;
    const int wid  = t >> 6;
    const int lane = t & 63;

    // Load + normalize both g vectors (each wave redundantly; 128 floats each).
    float2 gpv = reinterpret_cast<const float2*>(gp)[(size_t)s * 64 + lane];
    float2 gcv = reinterpret_cast<const float2*>(gc)[(size_t)s * 64 + lane];
    float gpss = wave_sum(gpv.x * gpv.x + gpv.y * gpv.y);
    float gcss = wave_sum(gcv.x * gcv.x + gcv.y * gcv.y);
    float invp = 1.0f / fmaxf(sqrtf(gpss), 1e-12f);
    float invc = 1.0f / fmaxf(sqrtf(gcss), 1e-12f);
    gpv.x *= invp; gpv.y *= invp;
    gcv.x *= invc; gcv.y *= invc;

    const float2* Z2 = reinterpret_cast<const float2*>(z);
    float acc = 0.f;
    for (int row = start + wid; row < end; row += 4) {
        float2 zv = Z2[(size_t)row * 64 + lane];
        float dp = zv.x * gpv.x + zv.y * gpv.y;
        float dc = zv.x * gcv.x + zv.y * gcv.y;
        float ss = zv.x * zv.x + zv.y * zv.y;
        dp = wave_sum(dp);
        dc = wave_sum(dc);
        ss = wave_sum(ss);
        float inv   = 1.0f / fmaxf(sqrtf(ss), 1e-12f);
        float pos   = dp * inv;
        float cross = dc * inv;
        // Ep(pos) - Ep(cross) = softplus(-cross) - softplus(-pos); args in ~[-1,1]
        float d = log1pf(__expf(-cross)) - log1pf(__expf(-pos));
        acc += d * d;   // identical across all 64 lanes after butterfly
    }

    __shared__ float wacc[4];
    if (lane == 0) wacc[wid] = acc;
    __syncthreads();
    if (t == 0) {
        float total = wacc[0] + wacc[1] + wacc[2] + wacc[3];
        atomicAdd(&sums[w], total);
    }
}

__global__ void finalize_kernel(const float* __restrict__ sums,
                                float* __restrict__ out) {
    out[0] = sqrtf(sums[0]) + sqrtf(sums[1]);
}

extern "C" void kernel_launch(void* const* d_in, const int* in_sizes, int n_in,
                              void* d_out, int out_size, void* d_ws, size_t ws_size,
                              hipStream_t stream) {
    const float* z1 = (const float*)d_in[0];
    const float* z2 = (const float*)d_in[1];
    const int*   b1 = (const int*)d_in[2];
    const int*   b2 = (const int*)d_in[3];
    const int N = in_sizes[2];

    float* g1   = (float*)d_ws;                    // 512*128 floats
    float* g2   = g1 + NUM_GRAPHS * D;             // 512*128 floats
    float* sums = g2 + NUM_GRAPHS * D;             // 2 floats

    hipMemsetAsync(sums, 0, 2 * sizeof(float), stream);

    dim3 grid(NUM_GRAPHS, 2);
    seg_sum_kernel<<<grid, 256, 0, stream>>>(z1, z2, b1, b2, g1, g2, N);
    dots_kernel<<<grid, 256, 0, stream>>>(z1, z2, b1, b2, g1, g2, sums, N);
    finalize_kernel<<<1, 1, 0, stream>>>(sums, (float*)d_out);
}

// Round 2
// 70.277 us; speedup vs baseline: 1.9942x; 1.9942x over previous
//
#include <hip/hip_runtime.h>
#include <math.h>

#define NUM_GRAPHS 512
#define D 128
#define BLOCK 1024
#define GROUPS 16   // BLOCK/64 row-groups in the segment-sum phase

__device__ inline int lower_bound_i(const int* __restrict__ b, int n, int v) {
    int lo = 0, hi = n;
    while (lo < hi) {
        int mid = (lo + hi) >> 1;
        if (b[mid] < v) lo = mid + 1; else hi = mid;
    }
    return lo;
}

__device__ inline float wave_sum(float v) {
#pragma unroll
    for (int off = 32; off > 0; off >>= 1) v += __shfl_xor(v, off, 64);
    return v;
}

// One block per segment s. Phases:
//  A: segment-sum z1 rows -> g1buf (LDS), z2 rows -> g2buf (LDS). Coalesced float2.
//  B: inverse norms of g1/g2 (two waves, butterfly).
//  C: per-row dots: 4 lanes per row, float4 loads (re-read hits L2/L3),
//     g vectors broadcast from LDS, 2-shuffle quad reduction, JSD epilogue.
//  Block-reduce sum of d^2 per modality -> 2 atomicAdds.
__global__ __launch_bounds__(BLOCK) void fused_gcl(const float* __restrict__ z1,
                                                   const float* __restrict__ z2,
                                                   const int* __restrict__ b1,
                                                   const int* __restrict__ b2,
                                                   float* __restrict__ sums,
                                                   int N) {
    const int s = blockIdx.x;
    const int t = threadIdx.x;

    __shared__ int bounds[4];
    __shared__ float g1buf[D];
    __shared__ float g2buf[D];
    __shared__ float2 part[GROUPS][64];
    __shared__ float invs[2];
    __shared__ float waccum[GROUPS][2];

    if (t == 0) {
        bounds[0] = lower_bound_i(b1, N, s);
        bounds[1] = lower_bound_i(b1, N, s + 1);
        bounds[2] = lower_bound_i(b2, N, s);
        bounds[3] = lower_bound_i(b2, N, s + 1);
    }
    __syncthreads();
    const int s1 = bounds[0], e1 = bounds[1];
    const int s2 = bounds[2], e2 = bounds[3];

    const int grp = t >> 6;   // 0..15 (wave id)
    const int c   = t & 63;   // float2 column

    // ---- Phase A1: sum z1 rows of segment ----
    {
        const float2* Z = reinterpret_cast<const float2*>(z1);
        float2 acc = make_float2(0.f, 0.f);
        for (int row = s1 + grp; row < e1; row += GROUPS) {
            float2 v = Z[(size_t)row * 64 + c];
            acc.x += v.x; acc.y += v.y;
        }
        part[grp][c] = acc;
    }
    __syncthreads();
    if (grp == 0) {
        float2 a = part[0][c];
#pragma unroll
        for (int g = 1; g < GROUPS; ++g) { a.x += part[g][c].x; a.y += part[g][c].y; }
        g1buf[2 * c] = a.x; g1buf[2 * c + 1] = a.y;
    }
    __syncthreads();

    // ---- Phase A2: sum z2 rows of segment ----
    {
        const float2* Z = reinterpret_cast<const float2*>(z2);
        float2 acc = make_float2(0.f, 0.f);
        for (int row = s2 + grp; row < e2; row += GROUPS) {
            float2 v = Z[(size_t)row * 64 + c];
            acc.x += v.x; acc.y += v.y;
        }
        part[grp][c] = acc;
    }
    __syncthreads();
    if (grp == 0) {
        float2 a = part[0][c];
#pragma unroll
        for (int g = 1; g < GROUPS; ++g) { a.x += part[g][c].x; a.y += part[g][c].y; }
        g2buf[2 * c] = a.x; g2buf[2 * c + 1] = a.y;
    }
    __syncthreads();

    // ---- Phase B: inverse norms ----
    if (grp == 0) {
        float x = g1buf[2 * c], y = g1buf[2 * c + 1];
        float ss = wave_sum(x * x + y * y);
        if (c == 0) invs[0] = 1.0f / fmaxf(sqrtf(ss), 1e-12f);
    } else if (grp == 1) {
        float x = g2buf[2 * c], y = g2buf[2 * c + 1];
        float ss = wave_sum(x * x + y * y);
        if (c == 0) invs[1] = 1.0f / fmaxf(sqrtf(ss), 1e-12f);
    }
    __syncthreads();
    const float inv1 = invs[0], inv2 = invs[1];

    // ---- Phase C: per-row dots + JSD ----
    const int q   = t & 3;    // quarter of a row (32 floats)
    const int rid = t >> 2;   // 0..255
    const float4* G1 = reinterpret_cast<const float4*>(g1buf);
    const float4* G2 = reinterpret_cast<const float4*>(g2buf);

    float accA = 0.f, accB = 0.f;
    {
        const float4* Z = reinterpret_cast<const float4*>(z1);
        const int cnt = e1 - s1;
        for (int idx = rid; idx < cnt; idx += BLOCK / 4) {
            const int row = s1 + idx;
            float p = 0.f, cr = 0.f, ss = 0.f;
#pragma unroll
            for (int i = 0; i < 8; ++i) {
                float4 zv = Z[(size_t)row * 32 + q * 8 + i];
                float4 gp = G1[q * 8 + i];
                float4 gc = G2[q * 8 + i];
                p  += zv.x * gp.x + zv.y * gp.y + zv.z * gp.z + zv.w * gp.w;
                cr += zv.x * gc.x + zv.y * gc.y + zv.z * gc.z + zv.w * gc.w;
                ss += zv.x * zv.x + zv.y * zv.y + zv.z * zv.z + zv.w * zv.w;
            }
            p  += __shfl_xor(p, 1, 64);  p  += __shfl_xor(p, 2, 64);
            cr += __shfl_xor(cr, 1, 64); cr += __shfl_xor(cr, 2, 64);
            ss += __shfl_xor(ss, 1, 64); ss += __shfl_xor(ss, 2, 64);
            if (q == 0) {
                float invz  = 1.0f / fmaxf(sqrtf(ss), 1e-12f);
                float pos   = p  * inv1 * invz;
                float cross = cr * inv2 * invz;
                float d = log1pf(__expf(-cross)) - log1pf(__expf(-pos));
                accA += d * d;
            }
        }
    }
    {
        const float4* Z = reinterpret_cast<const float4*>(z2);
        const int cnt = e2 - s2;
        for (int idx = rid; idx < cnt; idx += BLOCK / 4) {
            const int row = s2 + idx;
            float p = 0.f, cr = 0.f, ss = 0.f;
#pragma unroll
            for (int i = 0; i < 8; ++i) {
                float4 zv = Z[(size_t)row * 32 + q * 8 + i];
                float4 gp = G2[q * 8 + i];
                float4 gc = G1[q * 8 + i];
                p  += zv.x * gp.x + zv.y * gp.y + zv.z * gp.z + zv.w * gp.w;
                cr += zv.x * gc.x + zv.y * gc.y + zv.z * gc.z + zv.w * gc.w;
                ss += zv.x * zv.x + zv.y * zv.y + zv.z * zv.z + zv.w * zv.w;
            }
            p  += __shfl_xor(p, 1, 64);  p  += __shfl_xor(p, 2, 64);
            cr += __shfl_xor(cr, 1, 64); cr += __shfl_xor(cr, 2, 64);
            ss += __shfl_xor(ss, 1, 64); ss += __shfl_xor(ss, 2, 64);
            if (q == 0) {
                float invz  = 1.0f / fmaxf(sqrtf(ss), 1e-12f);
                float pos   = p  * inv2 * invz;
                float cross = cr * inv1 * invz;
                float d = log1pf(__expf(-cross)) - log1pf(__expf(-pos));
                accB += d * d;
            }
        }
    }

    // ---- Block reduction of the two d^2 sums ----
    accA = wave_sum(accA);
    accB = wave_sum(accB);
    if (c == 0) { waccum[grp][0] = accA; waccum[grp][1] = accB; }
    __syncthreads();
    if (t == 0) {
        float a = 0.f, b = 0.f;
#pragma unroll
        for (int g = 0; g < GROUPS; ++g) { a += waccum[g][0]; b += waccum[g][1]; }
        atomicAdd(&sums[0], a);
        atomicAdd(&sums[1], b);
    }
}

__global__ void finalize_kernel(const float* __restrict__ sums,
                                float* __restrict__ out) {
    out[0] = sqrtf(sums[0]) + sqrtf(sums[1]);
}

extern "C" void kernel_launch(void* const* d_in, const int* in_sizes, int n_in,
                              void* d_out, int out_size, void* d_ws, size_t ws_size,
                              hipStream_t stream) {
    const float* z1 = (const float*)d_in[0];
    const float* z2 = (const float*)d_in[1];
    const int*   b1 = (const int*)d_in[2];
    const int*   b2 = (const int*)d_in[3];
    const int N = in_sizes[2];

    float* sums = (float*)d_ws;
    hipMemsetAsync(sums, 0, 2 * sizeof(float), stream);

    fused_gcl<<<NUM_GRAPHS, BLOCK, 0, stream>>>(z1, z2, b1, b2, sums, N);
    finalize_kernel<<<1, 1, 0, stream>>>(sums, (float*)d_out);
}

// Round 3
// 60.943 us; speedup vs baseline: 2.2996x; 1.1532x over previous
//
#include <hip/hip_runtime.h>
#include <math.h>

#define NUM_GRAPHS 512
#define D 128

__device__ inline int lower_bound_i(const int* __restrict__ b, int n, int v) {
    int lo = 0, hi = n;
    while (lo < hi) {
        int mid = (lo + hi) >> 1;
        if (b[mid] < v) lo = mid + 1; else hi = mid;
    }
    return lo;
}

__device__ inline void add4(float4& a, const float4 v) {
    a.x += v.x; a.y += v.y; a.z += v.z; a.w += v.w;
}

// K0: one binary search per (segment, modality). off[0..511]=starts in b1,
// off[512..1023]=starts in b2.
__global__ void bounds_kernel(const int* __restrict__ b1,
                              const int* __restrict__ b2,
                              int* __restrict__ off, int N) {
    const int t = blockIdx.x * blockDim.x + threadIdx.x;
    if (t < NUM_GRAPHS)            off[t] = lower_bound_i(b1, N, t);
    else if (t < 2 * NUM_GRAPHS)   off[t] = lower_bound_i(b2, N, t - NUM_GRAPHS);
}

// K1: segment sum + L2-normalize, store normalized g. grid (512,2), block 256.
// Thread t: row-group r=t>>5 (8 rows/iter-group), float4 col c=t&31.
// 4 independent accumulators -> 4 loads in flight per lane.
__global__ __launch_bounds__(256) void seg_norm_kernel(const float* __restrict__ z1,
                                                       const float* __restrict__ z2,
                                                       const int* __restrict__ off,
                                                       float* __restrict__ g1n,
                                                       float* __restrict__ g2n,
                                                       int N) {
    const int s = blockIdx.x;
    const int w = blockIdx.y;
    const float* z = w ? z2 : z1;
    float*       g = w ? g2n : g1n;
    const int*   o = off + w * NUM_GRAPHS;
    const int start = o[s];
    const int end   = (s == NUM_GRAPHS - 1) ? N : o[s + 1];

    const int t = threadIdx.x;
    const int r = t >> 5;   // 0..7
    const int c = t & 31;   // float4 col
    const float4* Z = reinterpret_cast<const float4*>(z);

    float4 a0 = make_float4(0.f, 0.f, 0.f, 0.f), a1 = a0, a2 = a0, a3 = a0;
    int row = start + r;
    for (; row + 24 < end; row += 32) {
        float4 v0 = Z[(size_t)row * 32 + c];
        float4 v1 = Z[(size_t)(row + 8)  * 32 + c];
        float4 v2 = Z[(size_t)(row + 16) * 32 + c];
        float4 v3 = Z[(size_t)(row + 24) * 32 + c];
        add4(a0, v0); add4(a1, v1); add4(a2, v2); add4(a3, v3);
    }
    for (; row < end; row += 8) add4(a0, Z[(size_t)row * 32 + c]);
    add4(a0, a1); add4(a2, a3); add4(a0, a2);

    __shared__ float4 part[8][32];
    part[r][c] = a0;
    __syncthreads();
    if (t < 32) {
        float4 sum = part[0][t];
#pragma unroll
        for (int gg = 1; gg < 8; ++gg) add4(sum, part[gg][t]);
        float ss = sum.x * sum.x + sum.y * sum.y + sum.z * sum.z + sum.w * sum.w;
#pragma unroll
        for (int m = 1; m <= 16; m <<= 1) ss += __shfl_xor(ss, m, 64);
        const float inv = 1.0f / fmaxf(sqrtf(ss), 1e-12f);
        sum.x *= inv; sum.y *= inv; sum.z *= inv; sum.w *= inv;
        reinterpret_cast<float4*>(g)[(size_t)s * 32 + t] = sum;
    }
}

// K2: per-row dots + JSD. grid (512,2), block 256. Quad-per-row: q=t&3 owns
// 32 floats (8 float4). g vectors live in registers (loaded once per block).
__global__ __launch_bounds__(256) void dots_kernel(const float* __restrict__ z1,
                                                   const float* __restrict__ z2,
                                                   const int* __restrict__ off,
                                                   const float* __restrict__ g1n,
                                                   const float* __restrict__ g2n,
                                                   float* __restrict__ sums,
                                                   int N) {
    const int s = blockIdx.x;
    const int w = blockIdx.y;
    const float* z  = w ? z2 : z1;
    const float* gp = w ? g2n : g1n;
    const float* gc = w ? g1n : g2n;
    const int*   o  = off + w * NUM_GRAPHS;
    const int start = o[s];
    const int end   = (s == NUM_GRAPHS - 1) ? N : o[s + 1];

    const int t   = threadIdx.x;
    const int q   = t & 3;
    const int rid = t >> 2;

    float4 gpv[8], gcv[8];
    {
        const float4* GP = reinterpret_cast<const float4*>(gp) + (size_t)s * 32 + q * 8;
        const float4* GC = reinterpret_cast<const float4*>(gc) + (size_t)s * 32 + q * 8;
#pragma unroll
        for (int i = 0; i < 8; ++i) { gpv[i] = GP[i]; gcv[i] = GC[i]; }
    }

    const float4* Z = reinterpret_cast<const float4*>(z);
    float acc = 0.f;
    for (int row = start + rid; row < end; row += 64) {
        float p = 0.f, cr = 0.f, ss = 0.f;
#pragma unroll
        for (int i = 0; i < 8; ++i) {
            float4 zv = Z[(size_t)row * 32 + q * 8 + i];
            p  += zv.x * gpv[i].x + zv.y * gpv[i].y + zv.z * gpv[i].z + zv.w * gpv[i].w;
            cr += zv.x * gcv[i].x + zv.y * gcv[i].y + zv.z * gcv[i].z + zv.w * gcv[i].w;
            ss += zv.x * zv.x + zv.y * zv.y + zv.z * zv.z + zv.w * zv.w;
        }
        p  += __shfl_xor(p, 1, 64);  p  += __shfl_xor(p, 2, 64);
        cr += __shfl_xor(cr, 1, 64); cr += __shfl_xor(cr, 2, 64);
        ss += __shfl_xor(ss, 1, 64); ss += __shfl_xor(ss, 2, 64);
        if (q == 0) {
            const float invz  = 1.0f / fmaxf(sqrtf(ss), 1e-12f);
            const float pos   = p  * invz;
            const float cross = cr * invz;
            const float d = log1pf(__expf(-cross)) - log1pf(__expf(-pos));
            acc += d * d;
        }
    }

    // block reduce (acc nonzero only on q==0 lanes; butterfly sums them all)
#pragma unroll
    for (int m = 1; m <= 32; m <<= 1) acc += __shfl_xor(acc, m, 64);
    __shared__ float warr[4];
    if ((t & 63) == 0) warr[t >> 6] = acc;
    __syncthreads();
    if (t == 0) atomicAdd(&sums[w], warr[0] + warr[1] + warr[2] + warr[3]);
}

__global__ void finalize_kernel(const float* __restrict__ sums,
                                float* __restrict__ out) {
    out[0] = sqrtf(sums[0]) + sqrtf(sums[1]);
}

extern "C" void kernel_launch(void* const* d_in, const int* in_sizes, int n_in,
                              void* d_out, int out_size, void* d_ws, size_t ws_size,
                              hipStream_t stream) {
    const float* z1 = (const float*)d_in[0];
    const float* z2 = (const float*)d_in[1];
    const int*   b1 = (const int*)d_in[2];
    const int*   b2 = (const int*)d_in[3];
    const int N = in_sizes[2];

    int*   off  = (int*)d_ws;                          // 1024 ints
    float* g1n  = (float*)(off + 2 * NUM_GRAPHS);      // 512*128 floats
    float* g2n  = g1n + NUM_GRAPHS * D;                // 512*128 floats
    float* sums = g2n + NUM_GRAPHS * D;                // 2 floats

    hipMemsetAsync(sums, 0, 2 * sizeof(float), stream);

    bounds_kernel<<<4, 256, 0, stream>>>(b1, b2, off, N);
    dim3 grid(NUM_GRAPHS, 2);
    seg_norm_kernel<<<grid, 256, 0, stream>>>(z1, z2, off, g1n, g2n, N);
    dots_kernel<<<grid, 256, 0, stream>>>(z1, z2, off, g1n, g2n, sums, N);
    finalize_kernel<<<1, 1, 0, stream>>>(sums, (float*)d_out);
}